// Round 2
// baseline (406.614 us; speedup 1.0000x reference)
//
#include <hip/hip_runtime.h>
#include <hip/hip_bf16.h>

// B=16, S=512, D=64, V=32000.
// embed(norm) -> dist-softmax attn -> 2x (0.1*attn@(h@W^T)) -> logits = h2 @ out_w^T
// f32 everywhere except final GEMM operands (bf16 MFMA, f32 accum).
// Large scratch lives in the TAIL of d_out (fully consumed before the logits
// kernel overwrites all of d_out). Only hb/wb/n2 (~5.2MB) use d_ws.

#define S_ 512
#define D_ 64
#define V_ 32000

typedef __attribute__((ext_vector_type(8))) short short8_t;
typedef __attribute__((ext_vector_type(8))) __bf16 bf16x8;
typedef __attribute__((ext_vector_type(4))) float f32x4;

__device__ inline unsigned short f2bf(float x) {
    __hip_bfloat16 h = __float2bfloat16(x);
    return __builtin_bit_cast(unsigned short, h);
}

// ---------------- embed: emb[row][d], n2[row] ----------------
__global__ __launch_bounds__(256) void embed_kernel(const int* __restrict__ tokens,
                                                    const float* __restrict__ temb,
                                                    float* __restrict__ emb,
                                                    float* __restrict__ n2) {
    int row  = blockIdx.x * 4 + (threadIdx.x >> 6);
    int lane = threadIdx.x & 63;
    int s    = row & (S_ - 1);
    int tok  = tokens[row];
    float val;
    if (lane < 2) {
        float fs    = (float)s;
        float theta = 6.283185307179586f * (fs * (1.0f / 512.0f));
        float r     = 0.3f + 0.6f * (fs * (1.0f / 511.0f));
        val = (lane == 0) ? r * cosf(theta) : r * sinf(theta);
    } else {
        val = temb[tok * D_ + lane - 2];
    }
    float ss = val * val;
#pragma unroll
    for (int off = 32; off; off >>= 1) ss += __shfl_xor(ss, off, 64);
    float nrm = sqrtf(fmaxf(ss, 1e-12f));
    float e   = val / nrm;
    emb[row * D_ + lane] = e;
    float nn = e * e;
#pragma unroll
    for (int off = 32; off; off >>= 1) nn += __shfl_xor(nn, off, 64);
    if (lane == 0) n2[row] = nn;
}

// ---------------- attention: attn[b][q][k] = softmax_k(-dist) ----------------
__global__ __launch_bounds__(256) void attn_kernel(const float* __restrict__ emb,
                                                   const float* __restrict__ n2,
                                                   float* __restrict__ attn) {
    __shared__ float qs[16][65];
    __shared__ float ks[64][65];
    __shared__ float sc[16][516];
    __shared__ float n2qs[16];
    __shared__ float n2ks[64];
    int b  = blockIdx.x >> 5;
    int q0 = (blockIdx.x & 31) * 16;
    int t  = threadIdx.x;
    const float* ebase = emb + (size_t)b * S_ * D_;
#pragma unroll
    for (int j = 0; j < 4; ++j) {
        int idx = t + j * 256;
        qs[idx >> 6][idx & 63] = ebase[(q0 + (idx >> 6)) * D_ + (idx & 63)];
    }
    if (t < 16) n2qs[t] = n2[b * S_ + q0 + t];

    for (int kt = 0; kt < 8; ++kt) {
        int k0 = kt * 64;
        __syncthreads();
#pragma unroll
        for (int j = 0; j < 16; ++j) {
            int idx = t + j * 256;
            ks[idx >> 6][idx & 63] = ebase[(k0 + (idx >> 6)) * D_ + (idx & 63)];
        }
        if (t < 64) n2ks[t] = n2[b * S_ + k0 + t];
        __syncthreads();
        int q = t >> 4, ksub = t & 15;
#pragma unroll
        for (int j = 0; j < 4; ++j) {
            int k = ksub * 4 + j;
            float dot = 0.f;
#pragma unroll
            for (int d = 0; d < 64; ++d) dot = fmaf(qs[q][d], ks[k][d], dot);
            float sq = n2qs[q] + n2ks[k] - 2.0f * dot;
            float sv = (q0 + q == k0 + k) ? 0.0f : -sqrtf(fmaxf(sq, 1e-12f));
            sc[q][k0 + k] = sv;
        }
    }
    __syncthreads();
    int wave = t >> 6, lane = t & 63;
    for (int r = 0; r < 4; ++r) {
        int q = wave * 4 + r;
        float ex[8];
        float sum = 0.f;
#pragma unroll
        for (int i = 0; i < 8; ++i) {
            ex[i] = expf(sc[q][lane + i * 64]);   // row max is exactly 0 (diagonal)
            sum += ex[i];
        }
#pragma unroll
        for (int off = 32; off; off >>= 1) sum += __shfl_xor(sum, off, 64);
        float inv = 1.0f / sum;
#pragma unroll
        for (int i = 0; i < 8; ++i)
            attn[((size_t)(b * S_ + q0 + q)) * S_ + lane + i * 64] = ex[i] * inv;
    }
}

// ---------------- proj: out = h @ w^T  ([16 rows/block]) ----------------
__global__ __launch_bounds__(256) void proj_kernel(const float* __restrict__ h,
                                                   const float* __restrict__ w,
                                                   float* __restrict__ out) {
    __shared__ float ws[64][65];
    __shared__ float hs[16][65];
    int t  = threadIdx.x;
    int r0 = blockIdx.x * 16;
#pragma unroll
    for (int j = 0; j < 16; ++j) {
        int idx = t + j * 256;
        ws[idx >> 6][idx & 63] = w[idx];
    }
#pragma unroll
    for (int j = 0; j < 4; ++j) {
        int idx = t + j * 256;
        hs[idx >> 6][idx & 63] = h[r0 * D_ + idx];
    }
    __syncthreads();
    int d = t & 63, qg = t >> 6;
#pragma unroll
    for (int j = 0; j < 4; ++j) {
        int q = qg * 4 + j;
        float acc = 0.f;
#pragma unroll
        for (int e = 0; e < 64; ++e) acc = fmaf(hs[q][e], ws[d][e], acc);
        out[(r0 + q) * D_ + d] = acc;
    }
}

// ---------------- prop: out = scale * attn @ t  (per batch) ----------------
__global__ __launch_bounds__(256) void prop_kernel(const float* __restrict__ attn,
                                                   const float* __restrict__ tmat,
                                                   const float* __restrict__ edge_scale,
                                                   float* __restrict__ out) {
    __shared__ float As[32][65];
    __shared__ float Ts[64][65];
    int b  = blockIdx.x >> 4;
    int q0 = (blockIdx.x & 15) * 32;
    int t  = threadIdx.x;
    int d = t & 63, qg = t >> 6;
    float acc[8];
#pragma unroll
    for (int i = 0; i < 8; ++i) acc[i] = 0.f;
    const float* abase = attn + ((size_t)b * S_ + q0) * S_;
    const float* tbase = tmat + (size_t)b * S_ * D_;
    for (int kt = 0; kt < 8; ++kt) {
        __syncthreads();
#pragma unroll
        for (int j = 0; j < 8; ++j) {
            int idx = t + j * 256;
            As[idx >> 6][idx & 63] = abase[(size_t)(idx >> 6) * S_ + kt * 64 + (idx & 63)];
        }
#pragma unroll
        for (int j = 0; j < 16; ++j) {
            int idx = t + j * 256;
            Ts[idx >> 6][idx & 63] = tbase[(kt * 64 + (idx >> 6)) * D_ + (idx & 63)];
        }
        __syncthreads();
#pragma unroll
        for (int k = 0; k < 64; ++k) {
            float tv = Ts[k][d];
#pragma unroll
            for (int jj = 0; jj < 8; ++jj)
                acc[jj] = fmaf(As[qg * 8 + jj][k], tv, acc[jj]);
        }
    }
    float scale = edge_scale[0];
#pragma unroll
    for (int jj = 0; jj < 8; ++jj)
        out[((size_t)(b * S_ + q0 + qg * 8 + jj)) * D_ + d] = scale * acc[jj];
}

// ---------------- f32 -> bf16 cast ----------------
__global__ __launch_bounds__(256) void cast_kernel(const float* __restrict__ in,
                                                   unsigned short* __restrict__ out, int n) {
    int i = (blockIdx.x * 256 + threadIdx.x) * 4;
    if (i >= n) return;
    float4 v = *reinterpret_cast<const float4*>(in + i);
    ushort4 r;
    r.x = f2bf(v.x); r.y = f2bf(v.y); r.z = f2bf(v.z); r.w = f2bf(v.w);
    *reinterpret_cast<ushort4*>(out + i) = r;
}

// ---------------- logits: out[8192,32000] = h2 @ out_w^T  (bf16 MFMA) ----------------
// Swapped operands: D[n][m] = sum_k outw[n][k] * h2[m][k]. C/D layout (m89):
// "col"=lane&15 -> m, "row"=(lane>>4)*4+reg -> n  => each lane holds 4
// consecutive vocab columns for one output row -> float4 stores.
__global__ __launch_bounds__(256) void logits_kernel(const unsigned short* __restrict__ hb,
                                                     const unsigned short* __restrict__ wb,
                                                     float* __restrict__ out) {
    int bid = blockIdx.x;
    int nt = bid % 250, mt = bid / 250;
    int n0 = nt * 128, m0 = mt * 128;
    int wave = threadIdx.x >> 6, lane = threadIdx.x & 63;
    int nw = n0 + wave * 32;                 // this wave: 32 vocab cols x 128 rows
    int lr = lane & 15, lh = lane >> 4;

    // A-frag: out_w rows (the n dimension)
    bf16x8 a[2][2];
#pragma unroll
    for (int ns = 0; ns < 2; ++ns)
#pragma unroll
        for (int kh = 0; kh < 2; ++kh)
            a[ns][kh] = *reinterpret_cast<const bf16x8*>(
                wb + (size_t)(nw + ns * 16 + lr) * D_ + kh * 32 + lh * 8);

    // B-frag: h2 rows (the m dimension)
    bf16x8 bfr[8][2];
#pragma unroll
    for (int ms = 0; ms < 8; ++ms)
#pragma unroll
        for (int kh = 0; kh < 2; ++kh)
            bfr[ms][kh] = *reinterpret_cast<const bf16x8*>(
                hb + (size_t)(m0 + ms * 16 + lr) * D_ + kh * 32 + lh * 8);

    f32x4 acc[2][8];
#pragma unroll
    for (int ns = 0; ns < 2; ++ns)
#pragma unroll
        for (int ms = 0; ms < 8; ++ms)
            acc[ns][ms] = (f32x4){0.f, 0.f, 0.f, 0.f};

#pragma unroll
    for (int ns = 0; ns < 2; ++ns)
#pragma unroll
        for (int ms = 0; ms < 8; ++ms) {
            acc[ns][ms] = __builtin_amdgcn_mfma_f32_16x16x32_bf16(a[ns][0], bfr[ms][0], acc[ns][ms], 0, 0, 0);
            acc[ns][ms] = __builtin_amdgcn_mfma_f32_16x16x32_bf16(a[ns][1], bfr[ms][1], acc[ns][ms], 0, 0, 0);
        }

#pragma unroll
    for (int ns = 0; ns < 2; ++ns) {
        int colbase = nw + ns * 16 + lh * 4;
#pragma unroll
        for (int ms = 0; ms < 8; ++ms) {
            int row = m0 + ms * 16 + lr;
            f32x4 v = acc[ns][ms];
            *reinterpret_cast<float4*>(out + (size_t)row * V_ + colbase) =
                make_float4(v[0], v[1], v[2], v[3]);
        }
    }
}

extern "C" void kernel_launch(void* const* d_in, const int* in_sizes, int n_in,
                              void* d_out, int out_size, void* d_ws, size_t ws_size,
                              hipStream_t stream) {
    const int*   tokens = (const int*)d_in[0];
    const float* temb   = (const float*)d_in[1];
    const float* w1     = (const float*)d_in[2];
    const float* w2     = (const float*)d_in[3];
    const float* escale = (const float*)d_in[4];
    const float* outw   = (const float*)d_in[5];
    float*       out    = (float*)d_out;

    // Large scratch in tail of d_out (1,048,576,000 bytes); consumed before
    // logits_kernel rewrites every output element.
    char* tail = (char*)d_out + 1048576000ull - 25165824ull;
    float* attn = (float*)(tail);                   // 16 MB
    float* emb  = (float*)(tail + 16777216);        // 2 MB
    float* t1   = (float*)(tail + 18874368);        // 2 MB
    float* h1   = (float*)(tail + 20971520);        // 2 MB
    float* h2   = (float*)(tail + 23068672);        // 2 MB (ends exactly at out end)

    // Small scratch in d_ws (~5.2 MB): read by the logits kernel.
    char* ws = (char*)d_ws;
    unsigned short* hb = (unsigned short*)(ws);             // 1 MB
    unsigned short* wb = (unsigned short*)(ws + 1048576);   // 4 MB
    float*          n2 = (float*)(ws + 5144576);            // 32 KB

    embed_kernel<<<2048, 256, 0, stream>>>(tokens, temb, emb, n2);
    attn_kernel<<<512, 256, 0, stream>>>(emb, n2, attn);
    proj_kernel<<<512, 256, 0, stream>>>(emb, w1, t1);
    prop_kernel<<<256, 256, 0, stream>>>(attn, t1, escale, h1);
    proj_kernel<<<512, 256, 0, stream>>>(h1, w2, t1);
    prop_kernel<<<256, 256, 0, stream>>>(attn, t1, escale, h2);
    cast_kernel<<<512, 256, 0, stream>>>(h2, hb, 8192 * D_);
    cast_kernel<<<2000, 256, 0, stream>>>(outw, wb, V_ * D_);
    logits_kernel<<<16000, 256, 0, stream>>>(hb, wb, out);
}

// Round 3
// 347.229 us; speedup vs baseline: 1.1710x; 1.1710x over previous
//
#include <hip/hip_runtime.h>
#include <hip/hip_bf16.h>

// B=16, S=512, D=64, V=32000.
// embed(norm) -> dist-softmax attn -> 2x (0.1*attn@(h@W^T)) -> logits = h2 @ out_w^T
// Mid pipeline in f32 (register-blocked, b128 LDS); final GEMM bf16 MFMA f32-accum.
// Large scratch in tail of d_out (consumed before logits overwrites all of out);
// hb/wb/n2 (~5.2MB) in d_ws.

#define S_ 512
#define D_ 64
#define V_ 32000

typedef __attribute__((ext_vector_type(8))) __bf16 bf16x8;
typedef __attribute__((ext_vector_type(4))) float f32x4;

__device__ inline unsigned short f2bf(float x) {
    __hip_bfloat16 h = __float2bfloat16(x);
    return __builtin_bit_cast(unsigned short, h);
}

// ---------------- embed: emb[row][d], n2[row] ----------------
__global__ __launch_bounds__(256) void embed_kernel(const int* __restrict__ tokens,
                                                    const float* __restrict__ temb,
                                                    float* __restrict__ emb,
                                                    float* __restrict__ n2) {
    int row  = blockIdx.x * 4 + (threadIdx.x >> 6);
    int lane = threadIdx.x & 63;
    int s    = row & (S_ - 1);
    int tok  = tokens[row];
    float val;
    if (lane < 2) {
        float fs    = (float)s;
        float theta = 6.283185307179586f * (fs * (1.0f / 512.0f));
        float r     = 0.3f + 0.6f * (fs * (1.0f / 511.0f));
        val = (lane == 0) ? r * cosf(theta) : r * sinf(theta);
    } else {
        val = temb[tok * D_ + lane - 2];
    }
    float ss = val * val;
#pragma unroll
    for (int off = 32; off; off >>= 1) ss += __shfl_xor(ss, off, 64);
    float nrm = sqrtf(fmaxf(ss, 1e-12f));
    float e   = val / nrm;
    emb[row * D_ + lane] = e;
    float nn = e * e;
#pragma unroll
    for (int off = 32; off; off >>= 1) nn += __shfl_xor(nn, off, 64);
    if (lane == 0) n2[row] = nn;
}

// ---------------- attention: attn[b][q][k] = softmax_k(-dist) ----------------
// 2q x 2k register tile per thread, f32x4 vectorized over d.
__global__ __launch_bounds__(256) void attn_kernel(const float* __restrict__ emb,
                                                   const float* __restrict__ n2,
                                                   float* __restrict__ attn) {
    __shared__ float qs[16][68];
    __shared__ float ks[64][68];
    __shared__ float sc[16][520];
    __shared__ float n2qs[16];
    __shared__ float n2ks[64];
    int b  = blockIdx.x >> 5;
    int q0 = (blockIdx.x & 31) * 16;
    int t  = threadIdx.x;
    const float* ebase = emb + (size_t)b * S_ * D_;
    {   // stage q rows: 16x64 f32 = 256 float4, one per thread
        int r = t >> 4, c4 = (t & 15) * 4;
        *reinterpret_cast<float4*>(&qs[r][c4]) =
            *reinterpret_cast<const float4*>(&ebase[(q0 + r) * D_ + c4]);
    }
    if (t < 16) n2qs[t] = n2[b * S_ + q0 + t];

    int qh = t >> 5;   // 0..7 -> q = 2*qh + i
    int kh = t & 31;   // k = kh + 32*j

    for (int kt = 0; kt < 8; ++kt) {
        int k0 = kt * 64;
        __syncthreads();
#pragma unroll
        for (int j = 0; j < 4; ++j) {   // stage k rows: 64x64 = 1024 float4
            int f4 = t + j * 256;
            int r = f4 >> 4, c4 = (f4 & 15) * 4;
            *reinterpret_cast<float4*>(&ks[r][c4]) =
                *reinterpret_cast<const float4*>(&ebase[(k0 + r) * D_ + c4]);
        }
        if (t < 64) n2ks[t] = n2[b * S_ + k0 + t];
        __syncthreads();

        f32x4 acc[2][2];
#pragma unroll
        for (int i = 0; i < 2; ++i)
#pragma unroll
            for (int j = 0; j < 2; ++j) acc[i][j] = (f32x4){0.f, 0.f, 0.f, 0.f};
#pragma unroll
        for (int dc = 0; dc < 16; ++dc) {
            f32x4 qv0 = *reinterpret_cast<f32x4*>(&qs[2 * qh][dc * 4]);
            f32x4 qv1 = *reinterpret_cast<f32x4*>(&qs[2 * qh + 1][dc * 4]);
            f32x4 kv0 = *reinterpret_cast<f32x4*>(&ks[kh][dc * 4]);
            f32x4 kv1 = *reinterpret_cast<f32x4*>(&ks[kh + 32][dc * 4]);
            acc[0][0] += qv0 * kv0; acc[0][1] += qv0 * kv1;
            acc[1][0] += qv1 * kv0; acc[1][1] += qv1 * kv1;
        }
#pragma unroll
        for (int i = 0; i < 2; ++i)
#pragma unroll
            for (int j = 0; j < 2; ++j) {
                int q = 2 * qh + i, k = kh + 32 * j;
                f32x4 a = acc[i][j];
                float dot = (a[0] + a[1]) + (a[2] + a[3]);
                float sq  = n2qs[q] + n2ks[k] - 2.0f * dot;
                float sv  = (q0 + q == k0 + k) ? 0.0f : -sqrtf(fmaxf(sq, 1e-12f));
                sc[q][k0 + k] = sv;
            }
    }
    __syncthreads();
    int wave = t >> 6, lane = t & 63;
    for (int r = 0; r < 4; ++r) {
        int q = wave * 4 + r;
        float ex[8];
        float sum = 0.f;
#pragma unroll
        for (int i = 0; i < 8; ++i) {
            ex[i] = expf(sc[q][lane + i * 64]);   // row max is exactly 0 (diagonal)
            sum += ex[i];
        }
#pragma unroll
        for (int off = 32; off; off >>= 1) sum += __shfl_xor(sum, off, 64);
        float inv = 1.0f / sum;
#pragma unroll
        for (int i = 0; i < 8; ++i)
            attn[((size_t)(b * S_ + q0 + q)) * S_ + lane + i * 64] = ex[i] * inv;
    }
}

// ---------------- proj: out = h @ w^T  (16 rows/block, e-vectorized) ----------------
__global__ __launch_bounds__(256) void proj_kernel(const float* __restrict__ h,
                                                   const float* __restrict__ w,
                                                   float* __restrict__ out) {
    __shared__ float ws[64][68];
    __shared__ float hs[16][68];
    int t  = threadIdx.x;
    int r0 = blockIdx.x * 16;
#pragma unroll
    for (int j = 0; j < 4; ++j) {   // ws: 64x64 = 1024 float4
        int f4 = t + j * 256;
        int r = f4 >> 4, c4 = (f4 & 15) * 4;
        *reinterpret_cast<float4*>(&ws[r][c4]) =
            *reinterpret_cast<const float4*>(&w[r * D_ + c4]);
    }
    {   // hs: 16x64 = 256 float4
        int r = t >> 4, c4 = (t & 15) * 4;
        *reinterpret_cast<float4*>(&hs[r][c4]) =
            *reinterpret_cast<const float4*>(&h[(r0 + r) * D_ + c4]);
    }
    __syncthreads();
    int q = t >> 4, dh = t & 15;    // thread: 1 q x 4 d
    f32x4 acc[4];
#pragma unroll
    for (int dj = 0; dj < 4; ++dj) acc[dj] = (f32x4){0.f, 0.f, 0.f, 0.f};
#pragma unroll
    for (int ec = 0; ec < 16; ++ec) {
        f32x4 hv = *reinterpret_cast<f32x4*>(&hs[q][ec * 4]);
#pragma unroll
        for (int dj = 0; dj < 4; ++dj) {
            f32x4 wv = *reinterpret_cast<f32x4*>(&ws[dh * 4 + dj][ec * 4]);
            acc[dj] += hv * wv;
        }
    }
    float4 r;
    r.x = (acc[0][0] + acc[0][1]) + (acc[0][2] + acc[0][3]);
    r.y = (acc[1][0] + acc[1][1]) + (acc[1][2] + acc[1][3]);
    r.z = (acc[2][0] + acc[2][1]) + (acc[2][2] + acc[2][3]);
    r.w = (acc[3][0] + acc[3][1]) + (acc[3][2] + acc[3][3]);
    *reinterpret_cast<float4*>(&out[(r0 + q) * D_ + dh * 4]) = r;
}

// ---------------- prop: out = scale * attn @ t  (16 q-rows/block, k-vectorized) --------
template <bool BF16OUT>
__global__ __launch_bounds__(256) void prop_kernel(const float* __restrict__ attn,
                                                   const float* __restrict__ tmat,
                                                   const float* __restrict__ edge_scale,
                                                   float* __restrict__ outf,
                                                   unsigned short* __restrict__ outb) {
    __shared__ float As[16][68];
    __shared__ float Ts[64][68];
    int b  = blockIdx.x >> 5;
    int q0 = (blockIdx.x & 31) * 16;
    int t  = threadIdx.x;
    int q = t >> 4, dh = t & 15;    // thread: 1 q x 4 d
    f32x4 acc = (f32x4){0.f, 0.f, 0.f, 0.f};
    const float* abase = attn + ((size_t)b * S_ + q0) * S_;
    const float* tbase = tmat + (size_t)b * S_ * D_;
    for (int kt = 0; kt < 8; ++kt) {
        int k0 = kt * 64;
        __syncthreads();
        {   // As: 16 rows x 64 cols = 256 float4
            int r = t >> 4, c4 = (t & 15) * 4;
            *reinterpret_cast<float4*>(&As[r][c4]) =
                *reinterpret_cast<const float4*>(&abase[(size_t)r * S_ + k0 + c4]);
        }
#pragma unroll
        for (int j = 0; j < 4; ++j) {   // Ts: 64x64 = 1024 float4
            int f4 = t + j * 256;
            int r = f4 >> 4, c4 = (f4 & 15) * 4;
            *reinterpret_cast<float4*>(&Ts[r][c4]) =
                *reinterpret_cast<const float4*>(&tbase[(k0 + r) * D_ + c4]);
        }
        __syncthreads();
#pragma unroll
        for (int kc = 0; kc < 16; ++kc) {
            f32x4 av = *reinterpret_cast<f32x4*>(&As[q][kc * 4]);
#pragma unroll
            for (int ks = 0; ks < 4; ++ks) {
                f32x4 tv = *reinterpret_cast<f32x4*>(&Ts[kc * 4 + ks][dh * 4]);
                acc += av[ks] * tv;
            }
        }
    }
    float scale = edge_scale[0];
    size_t rowbase = ((size_t)(b * S_ + q0 + q)) * D_ + dh * 4;
    if (BF16OUT) {
        ushort4 r;
        r.x = f2bf(scale * acc[0]); r.y = f2bf(scale * acc[1]);
        r.z = f2bf(scale * acc[2]); r.w = f2bf(scale * acc[3]);
        *reinterpret_cast<ushort4*>(&outb[rowbase]) = r;
    } else {
        *reinterpret_cast<float4*>(&outf[rowbase]) =
            make_float4(scale * acc[0], scale * acc[1], scale * acc[2], scale * acc[3]);
    }
}

// ---------------- f32 -> bf16 cast (out_w) ----------------
__global__ __launch_bounds__(256) void cast_kernel(const float* __restrict__ in,
                                                   unsigned short* __restrict__ out, int n) {
    int i = (blockIdx.x * 256 + threadIdx.x) * 4;
    if (i >= n) return;
    float4 v = *reinterpret_cast<const float4*>(in + i);
    ushort4 r;
    r.x = f2bf(v.x); r.y = f2bf(v.y); r.z = f2bf(v.z); r.w = f2bf(v.w);
    *reinterpret_cast<ushort4*>(out + i) = r;
}

// ---------------- logits: out[8192,32000] = h2 @ out_w^T  (bf16 MFMA) ----------------
// Swapped operands: D[n][m], lane holds 4 consecutive vocab cols of one row.
__global__ __launch_bounds__(256) void logits_kernel(const unsigned short* __restrict__ hb,
                                                     const unsigned short* __restrict__ wb,
                                                     float* __restrict__ out) {
    int bid = blockIdx.x;
    int nt = bid % 250, mt = bid / 250;
    int n0 = nt * 128, m0 = mt * 128;
    int wave = threadIdx.x >> 6, lane = threadIdx.x & 63;
    int nw = n0 + wave * 32;
    int lr = lane & 15, lh = lane >> 4;

    bf16x8 a[2][2];
#pragma unroll
    for (int ns = 0; ns < 2; ++ns)
#pragma unroll
        for (int kh = 0; kh < 2; ++kh)
            a[ns][kh] = *reinterpret_cast<const bf16x8*>(
                wb + (size_t)(nw + ns * 16 + lr) * D_ + kh * 32 + lh * 8);

    bf16x8 bfr[8][2];
#pragma unroll
    for (int ms = 0; ms < 8; ++ms)
#pragma unroll
        for (int kh = 0; kh < 2; ++kh)
            bfr[ms][kh] = *reinterpret_cast<const bf16x8*>(
                hb + (size_t)(m0 + ms * 16 + lr) * D_ + kh * 32 + lh * 8);

    f32x4 acc[2][8];
#pragma unroll
    for (int ns = 0; ns < 2; ++ns)
#pragma unroll
        for (int ms = 0; ms < 8; ++ms)
            acc[ns][ms] = (f32x4){0.f, 0.f, 0.f, 0.f};

#pragma unroll
    for (int ns = 0; ns < 2; ++ns)
#pragma unroll
        for (int ms = 0; ms < 8; ++ms) {
            acc[ns][ms] = __builtin_amdgcn_mfma_f32_16x16x32_bf16(a[ns][0], bfr[ms][0], acc[ns][ms], 0, 0, 0);
            acc[ns][ms] = __builtin_amdgcn_mfma_f32_16x16x32_bf16(a[ns][1], bfr[ms][1], acc[ns][ms], 0, 0, 0);
        }

#pragma unroll
    for (int ns = 0; ns < 2; ++ns) {
        int colbase = nw + ns * 16 + lh * 4;
#pragma unroll
        for (int ms = 0; ms < 8; ++ms) {
            int row = m0 + ms * 16 + lr;
            f32x4 v = acc[ns][ms];
            *reinterpret_cast<float4*>(out + (size_t)row * V_ + colbase) =
                make_float4(v[0], v[1], v[2], v[3]);
        }
    }
}

extern "C" void kernel_launch(void* const* d_in, const int* in_sizes, int n_in,
                              void* d_out, int out_size, void* d_ws, size_t ws_size,
                              hipStream_t stream) {
    const int*   tokens = (const int*)d_in[0];
    const float* temb   = (const float*)d_in[1];
    const float* w1     = (const float*)d_in[2];
    const float* w2     = (const float*)d_in[3];
    const float* escale = (const float*)d_in[4];
    const float* outw   = (const float*)d_in[5];
    float*       out    = (float*)d_out;

    // Large scratch in tail of d_out (1,048,576,000 B); consumed before logits.
    char* tail = (char*)d_out + 1048576000ull - 23068672ull;
    float* attn = (float*)(tail);                   // 16 MB
    float* emb  = (float*)(tail + 16777216);        // 2 MB
    float* t1   = (float*)(tail + 18874368);        // 2 MB
    float* h1   = (float*)(tail + 20971520);        // 2 MB (ends at out end)

    // Small scratch in d_ws (~5.2 MB): read by logits.
    char* ws = (char*)d_ws;
    unsigned short* hb = (unsigned short*)(ws);             // 1 MB
    unsigned short* wb = (unsigned short*)(ws + 1048576);   // 4 MB
    float*          n2 = (float*)(ws + 5144576);            // 32 KB

    embed_kernel<<<2048, 256, 0, stream>>>(tokens, temb, emb, n2);
    attn_kernel<<<512, 256, 0, stream>>>(emb, n2, attn);
    cast_kernel<<<2000, 256, 0, stream>>>(outw, wb, V_ * D_);
    proj_kernel<<<512, 256, 0, stream>>>(emb, w1, t1);
    prop_kernel<false><<<512, 256, 0, stream>>>(attn, t1, escale, h1, nullptr);
    proj_kernel<<<512, 256, 0, stream>>>(h1, w2, t1);
    prop_kernel<true><<<512, 256, 0, stream>>>(attn, t1, escale, nullptr, hb);
    logits_kernel<<<16000, 256, 0, stream>>>(hb, wb, out);
}